// Round 3
// baseline (193.922 us; speedup 1.0000x reference)
//
#include <hip/hip_runtime.h>
#include <math.h>

#define D      4096
#define NPREV  8191
#define NROWS  8192

// ---------------- out[m] = dot(W[m,:], v)  (+ optional residual) -------------
template<bool RESIDUAL>
__global__ void k_matvec_rows(const float* __restrict__ W, const float* __restrict__ v,
                              const float* __restrict__ resid, float* __restrict__ out) {
    int row  = (blockIdx.x * blockDim.x + threadIdx.x) >> 6;  // one wave per row
    int lane = threadIdx.x & 63;
    if (row >= D) return;
    const float4* Wrow = reinterpret_cast<const float4*>(W + (size_t)row * D);
    const float4* v4   = reinterpret_cast<const float4*>(v);
    float acc = 0.f;
    #pragma unroll 4
    for (int i = lane; i < D / 4; i += 64) {
        float4 w = Wrow[i], x = v4[i];
        acc += w.x * x.x + w.y * x.y + w.z * x.z + w.w * x.w;
    }
    #pragma unroll
    for (int off = 32; off; off >>= 1) acc += __shfl_down(acc, off, 64);
    if (lane == 0) out[row] = RESIDUAL ? (acc + resid[row]) : acc;
}

// ---------------- partial of kq[d] = sum_m q[m] * W[m][d] --------------------
template<int MCHUNK>
__global__ void k_colvec_partial(const float* __restrict__ W, const float* __restrict__ q,
                                 float* __restrict__ part) {
    int d4 = blockIdx.x * 256 + threadIdx.x;     // 0..1023 (float4 columns)
    int m0 = blockIdx.y * MCHUNK;
    const float4* W4 = reinterpret_cast<const float4*>(W);
    float4 acc = make_float4(0.f, 0.f, 0.f, 0.f);
    #pragma unroll 4
    for (int m = m0; m < m0 + MCHUNK; ++m) {
        float qm = q[m];
        float4 w = W4[(size_t)m * (D / 4) + d4];
        acc.x += qm * w.x; acc.y += qm * w.y; acc.z += qm * w.z; acc.w += qm * w.w;
    }
    reinterpret_cast<float4*>(part)[(size_t)blockIdx.y * (D / 4) + d4] = acc;
}

__global__ void k_reduce_chunks(const float* __restrict__ part, float* __restrict__ out,
                                int nchunks) {
    int d = blockIdx.x * 256 + threadIdx.x;      // 0..4095
    float acc = 0.f;
    #pragma unroll 8
    for (int c = 0; c < nchunks; ++c) acc += part[(size_t)c * D + d];
    out[d] = acc;
}

// ---------------- fused flash: copy + logits + block softmax + ctx partial ---
// FB blocks x THREADS threads; block owns FR = NROWS/FB consecutive rows.
template<int FB, int THREADS>
__global__ __launch_bounds__(THREADS, 8) void k_flash(
        const float* __restrict__ prev, const float* __restrict__ inp,
        const float* __restrict__ kq, float* __restrict__ io,
        float* __restrict__ ms, float* __restrict__ ctxpart) {
    constexpr int FR = NROWS / FB;
    constexpr int NW = THREADS / 64;
    constexpr int C4 = (D / 4) / THREADS;        // float4 columns per thread
    __shared__ float s_log[FR];
    __shared__ float s_e[FR];
    const int n0 = blockIdx.x * FR;
    const int t = threadIdx.x;
    const int wid = t >> 6, lane = t & 63;
    const float4* k4 = reinterpret_cast<const float4*>(kq);

    // Phase A: copy rows to io, logits into LDS (wave per row)
    for (int r = wid; r < FR; r += NW) {
        int n = n0 + r;
        const float4* s4 = reinterpret_cast<const float4*>(
            (n < NPREV) ? (prev + (size_t)n * D) : inp);
        float4* d4 = reinterpret_cast<float4*>(io + (size_t)n * D);
        float acc = 0.f;
        #pragma unroll 4
        for (int i = lane; i < D / 4; i += 64) {
            float4 x = s4[i], k = k4[i];
            d4[i] = x;
            acc += x.x * k.x + x.y * k.y + x.z * k.z + x.w * k.w;
        }
        #pragma unroll
        for (int off = 32; off; off >>= 1) acc += __shfl_down(acc, off, 64);
        if (lane == 0) s_log[r] = acc;
    }
    __syncthreads();

    // Phase B: block-local softmax stats
    float m_b = -INFINITY;
    #pragma unroll
    for (int r = 0; r < FR; ++r) m_b = fmaxf(m_b, s_log[r]);
    if (t < FR) s_e[t] = __expf(s_log[t] - m_b);
    __syncthreads();
    float s_b = 0.f;
    #pragma unroll
    for (int r = 0; r < FR; ++r) s_b += s_e[r];

    // Phase C: ctx partial over this block's rows (re-read prev: L3-hot)
    float4 acc[C4];
    #pragma unroll
    for (int c = 0; c < C4; ++c) acc[c] = make_float4(0.f, 0.f, 0.f, 0.f);
    #pragma unroll 4
    for (int r = 0; r < FR; ++r) {
        int n = n0 + r;
        const float4* s4 = reinterpret_cast<const float4*>(
            (n < NPREV) ? (prev + (size_t)n * D) : inp);
        float e = s_e[r];
        #pragma unroll
        for (int c = 0; c < C4; ++c) {
            float4 x = s4[t + c * THREADS];
            acc[c].x += e * x.x; acc[c].y += e * x.y;
            acc[c].z += e * x.z; acc[c].w += e * x.w;
        }
    }
    float4* cp = reinterpret_cast<float4*>(ctxpart + (size_t)blockIdx.x * D);
    #pragma unroll
    for (int c = 0; c < C4; ++c) cp[t + c * THREADS] = acc[c];
    if (t == 0) { ms[2 * blockIdx.x] = m_b; ms[2 * blockIdx.x + 1] = s_b; }
}

// ---------------- combine partials -> normalized ctx -------------------------
template<int FB>
__global__ void k_combine(const float* __restrict__ ms, const float* __restrict__ ctxpart,
                          float* __restrict__ ctx) {
    __shared__ float sm[2 * FB];
    int t = threadIdx.x;  // 256
    for (int i = t; i < 2 * FB; i += 256) sm[i] = ms[i];
    __syncthreads();
    float M = -INFINITY;
    #pragma unroll 8
    for (int b = 0; b < FB; ++b) M = fmaxf(M, sm[2 * b]);
    float S = 0.f;
    #pragma unroll 8
    for (int b = 0; b < FB; ++b) S += __expf(sm[2 * b] - M) * sm[2 * b + 1];
    int d4 = blockIdx.x * 256 + t;   // 4 blocks -> 1024 float4 columns
    float4 a = make_float4(0.f, 0.f, 0.f, 0.f);
    #pragma unroll 8
    for (int b = 0; b < FB; ++b) {
        float w = __expf(sm[2 * b] - M);
        float4 x = reinterpret_cast<const float4*>(ctxpart)[(size_t)b * (D / 4) + d4];
        a.x += w * x.x; a.y += w * x.y; a.z += w * x.z; a.w += w * x.w;
    }
    float inv = 1.f / S;
    a.x *= inv; a.y *= inv; a.z *= inv; a.w *= inv;
    reinterpret_cast<float4*>(ctx)[d4] = a;
}

// ---------------- pipeline ---------------------------------------------------
template<int MCHUNK, int FB, int THREADS>
static void run_pipeline(const float* prev, const float* inp, const float* W_Q,
                         const float* W_K, const float* W_V, float* out,
                         float* ws, hipStream_t stream) {
    float* query   = ws;                                   // D
    float* kq      = ws + D;                               // D
    float* kqpart  = ws + 2 * D;                           // (D/MCHUNK)*D
    float* ms      = kqpart + (size_t)(D / MCHUNK) * D;    // 2*FB
    float* ctxpart = ms + 2 * FB;                          // FB*D
    float* ctx     = ctxpart + (size_t)FB * D;             // D
    float* io      = out + D;

    k_matvec_rows<false><<<1024, 256, 0, stream>>>(W_Q, inp, nullptr, query);
    k_colvec_partial<MCHUNK><<<dim3(4, D / MCHUNK), 256, 0, stream>>>(W_K, query, kqpart);
    k_reduce_chunks<<<16, 256, 0, stream>>>(kqpart, kq, D / MCHUNK);
    k_flash<FB, THREADS><<<FB, THREADS, 0, stream>>>(prev, inp, kq, io, ms, ctxpart);
    k_combine<FB><<<4, 256, 0, stream>>>(ms, ctxpart, ctx);
    k_matvec_rows<true><<<1024, 256, 0, stream>>>(W_V, ctx, inp, out);
}

template<int MCHUNK, int FB>
static constexpr size_t ws_need() {
    return (size_t)(2 * D + (D / MCHUNK) * D + 2 * FB + (size_t)FB * D + D) * sizeof(float);
}

extern "C" void kernel_launch(void* const* d_in, const int* in_sizes, int n_in,
                              void* d_out, int out_size, void* d_ws, size_t ws_size,
                              hipStream_t stream) {
    const float* prev = (const float*)d_in[0];   // (8191, 4096)
    const float* inp  = (const float*)d_in[1];   // (4096,)
    const float* W_Q  = (const float*)d_in[2];
    const float* W_K  = (const float*)d_in[3];
    const float* W_V  = (const float*)d_in[4];
    float* out = (float*)d_out;                  // [0:4096]=output, [4096:]=inputs
    float* ws  = (float*)d_ws;

    if (ws_size >= ws_need<16, 512>()) {
        run_pipeline<16, 512, 1024>(prev, inp, W_Q, W_K, W_V, out, ws, stream);
    } else if (ws_size >= ws_need<64, 256>()) {
        run_pipeline<64, 256, 1024>(prev, inp, W_Q, W_K, W_V, out, ws, stream);
    } else {
        run_pipeline<64, 128, 512>(prev, inp, W_Q, W_K, W_V, out, ws, stream);
    }
}

// Round 5
// 178.284 us; speedup vs baseline: 1.0877x; 1.0877x over previous
//
#include <hip/hip_runtime.h>
#include <math.h>

#define D      4096
#define NPREV  8191
#define NROWS  8192

typedef float f4 __attribute__((ext_vector_type(4)));

static __device__ __forceinline__ f4 nt_load4(const float* p) {
    return __builtin_nontemporal_load(reinterpret_cast<const f4*>(p));
}
static __device__ __forceinline__ void nt_store4(f4 v, float* p) {
    __builtin_nontemporal_store(v, reinterpret_cast<f4*>(p));
}
static __device__ __forceinline__ f4 ld4(const float* p) {
    return *reinterpret_cast<const f4*>(p);
}
static __device__ __forceinline__ void st4(f4 v, float* p) {
    *reinterpret_cast<f4*>(p) = v;
}

// ---------------- out[m] = dot(W[m,:], v)  (+ optional residual) -------------
template<bool RESIDUAL>
__global__ void k_matvec_rows(const float* __restrict__ W, const float* __restrict__ v,
                              const float* __restrict__ resid, float* __restrict__ out) {
    int row  = (blockIdx.x * blockDim.x + threadIdx.x) >> 6;  // one wave per row
    int lane = threadIdx.x & 63;
    if (row >= D) return;
    const float* Wrow = W + (size_t)row * D;
    float acc = 0.f;
    #pragma unroll 4
    for (int i = lane; i < D / 4; i += 64) {
        f4 w = nt_load4(Wrow + 4 * i), x = ld4(v + 4 * i);
        acc += w.x * x.x + w.y * x.y + w.z * x.z + w.w * x.w;
    }
    #pragma unroll
    for (int off = 32; off; off >>= 1) acc += __shfl_down(acc, off, 64);
    if (lane == 0) out[row] = RESIDUAL ? (acc + resid[row]) : acc;
}

// ---------------- partial of kq[d] = sum_m q[m] * W[m][d] --------------------
template<int MCHUNK>
__global__ void k_colvec_partial(const float* __restrict__ W, const float* __restrict__ q,
                                 float* __restrict__ part) {
    int d4 = blockIdx.x * 256 + threadIdx.x;     // 0..1023 (float4 columns)
    int m0 = blockIdx.y * MCHUNK;
    f4 acc = (f4)0.f;
    #pragma unroll 4
    for (int m = m0; m < m0 + MCHUNK; ++m) {
        float qm = q[m];
        f4 w = nt_load4(W + (size_t)m * D + 4 * d4);
        acc += qm * w;
    }
    st4(acc, part + (size_t)blockIdx.y * D + 4 * d4);
}

__global__ void k_reduce_chunks(const float* __restrict__ part, float* __restrict__ out,
                                int nchunks) {
    int d = blockIdx.x * 256 + threadIdx.x;      // 0..4095
    float acc = 0.f;
    #pragma unroll 8
    for (int c = 0; c < nchunks; ++c) acc += part[(size_t)c * D + d];
    out[d] = acc;
}

// ---------------- single-pass register-resident flash ------------------------
// FB=512 blocks x 1024 threads; block owns FR=16 consecutive rows; thread t
// owns float4 column t of every row (held in registers through the kernel).
#define FB   512
#define FR   (NROWS / FB)   // 16
__global__ __launch_bounds__(1024, 4) void k_flash(
        const float* __restrict__ prev, const float* __restrict__ inp,
        const float* __restrict__ kq, float* __restrict__ io,
        float* __restrict__ ms, float* __restrict__ ctxpart) {
    __shared__ float s_wred[16][FR];
    __shared__ float s_log[FR];
    const int n0 = blockIdx.x * FR;
    const int t = threadIdx.x;
    const int wid = t >> 6, lane = t & 63;
    const f4 kqv = ld4(kq + 4 * t);

    // load all FR row-slices into registers (independent loads, deep ILP)
    f4 x[FR];
    #pragma unroll
    for (int r = 0; r < FR; ++r) {
        int n = n0 + r;
        const float* src = (n < NPREV) ? (prev + (size_t)n * D) : inp;
        x[r] = nt_load4(src + 4 * t);
    }
    // stream to io + per-row dot partials
    float p[FR];
    #pragma unroll
    for (int r = 0; r < FR; ++r) {
        int n = n0 + r;
        nt_store4(x[r], io + (size_t)n * D + 4 * t);
        p[r] = x[r].x * kqv.x + x[r].y * kqv.y + x[r].z * kqv.z + x[r].w * kqv.w;
    }
    // block reduction of each row's logit
    #pragma unroll
    for (int r = 0; r < FR; ++r) {
        float v = p[r];
        #pragma unroll
        for (int off = 32; off; off >>= 1) v += __shfl_down(v, off, 64);
        if (lane == 0) s_wred[wid][r] = v;
    }
    __syncthreads();
    if (t < FR) {
        float s = 0.f;
        #pragma unroll
        for (int w = 0; w < 16; ++w) s += s_wred[w][t];
        s_log[t] = s;
    }
    __syncthreads();
    // block-local softmax stats (every thread computes redundantly from LDS)
    float m_b = -INFINITY;
    #pragma unroll
    for (int r = 0; r < FR; ++r) m_b = fmaxf(m_b, s_log[r]);
    float e[FR], s_b = 0.f;
    #pragma unroll
    for (int r = 0; r < FR; ++r) { e[r] = __expf(s_log[r] - m_b); s_b += e[r]; }
    // weighted accumulate from registers — no re-read
    f4 a = (f4)0.f;
    #pragma unroll
    for (int r = 0; r < FR; ++r) a += e[r] * x[r];
    st4(a, ctxpart + (size_t)blockIdx.x * D + 4 * t);
    if (t == 0) { ms[2 * blockIdx.x] = m_b; ms[2 * blockIdx.x + 1] = s_b; }
}

// ---------------- combine stage 1: weight partials, sum 64 per block ---------
// grid (4, FB/64), 256 threads
__global__ void k_combine1(const float* __restrict__ ms, const float* __restrict__ ctxpart,
                           float* __restrict__ ctx2) {
    __shared__ float sm[2 * FB];
    int t = threadIdx.x;
    for (int i = t; i < 2 * FB; i += 256) sm[i] = ms[i];
    __syncthreads();
    float M = -INFINITY;
    #pragma unroll 8
    for (int b = 0; b < FB; ++b) M = fmaxf(M, sm[2 * b]);
    int d4 = blockIdx.x * 256 + t;
    int b0 = blockIdx.y * 64;
    f4 a = (f4)0.f;
    #pragma unroll 4
    for (int b = b0; b < b0 + 64; ++b) {
        float w = __expf(sm[2 * b] - M);
        f4 v = ld4(ctxpart + (size_t)b * D + 4 * d4);
        a += w * v;
    }
    st4(a, ctx2 + (size_t)blockIdx.y * D + 4 * d4);
}

// ---------------- combine stage 2: sum chunks, normalize ---------------------
// grid 4, 256 threads
__global__ void k_combine2(const float* __restrict__ ms, const float* __restrict__ ctx2,
                           float* __restrict__ ctx, int nchunks) {
    __shared__ float sm[2 * FB];
    int t = threadIdx.x;
    for (int i = t; i < 2 * FB; i += 256) sm[i] = ms[i];
    __syncthreads();
    float M = -INFINITY;
    #pragma unroll 8
    for (int b = 0; b < FB; ++b) M = fmaxf(M, sm[2 * b]);
    float S = 0.f;
    #pragma unroll 8
    for (int b = 0; b < FB; ++b) S += __expf(sm[2 * b] - M) * sm[2 * b + 1];
    int d4 = blockIdx.x * 256 + t;
    f4 a = (f4)0.f;
    for (int c = 0; c < nchunks; ++c) a += ld4(ctx2 + (size_t)c * D + 4 * d4);
    a *= (1.f / S);
    st4(a, ctx + 4 * d4);
}

// ---------------- legacy fallback flash (re-read variant, small ws) ----------
template<int FBL, int THREADS>
__global__ __launch_bounds__(THREADS, 8) void k_flash_legacy(
        const float* __restrict__ prev, const float* __restrict__ inp,
        const float* __restrict__ kq, float* __restrict__ io,
        float* __restrict__ ms, float* __restrict__ ctxpart) {
    constexpr int FRL = NROWS / FBL;
    constexpr int NW = THREADS / 64;
    constexpr int C4 = (D / 4) / THREADS;
    __shared__ float s_log[FRL];
    __shared__ float s_e[FRL];
    const int n0 = blockIdx.x * FRL;
    const int t = threadIdx.x;
    const int wid = t >> 6, lane = t & 63;
    for (int r = wid; r < FRL; r += NW) {
        int n = n0 + r;
        const float* src = (n < NPREV) ? (prev + (size_t)n * D) : inp;
        float acc = 0.f;
        #pragma unroll 4
        for (int i = lane; i < D / 4; i += 64) {
            f4 xx = ld4(src + 4 * i), k = ld4(kq + 4 * i);
            st4(xx, io + (size_t)n * D + 4 * i);
            acc += xx.x * k.x + xx.y * k.y + xx.z * k.z + xx.w * k.w;
        }
        #pragma unroll
        for (int off = 32; off; off >>= 1) acc += __shfl_down(acc, off, 64);
        if (lane == 0) s_log[r] = acc;
    }
    __syncthreads();
    float m_b = -INFINITY;
    #pragma unroll
    for (int r = 0; r < FRL; ++r) m_b = fmaxf(m_b, s_log[r]);
    if (t < FRL) s_e[t] = __expf(s_log[t] - m_b);
    __syncthreads();
    float s_b = 0.f;
    #pragma unroll
    for (int r = 0; r < FRL; ++r) s_b += s_e[r];
    f4 acc[C4];
    #pragma unroll
    for (int c = 0; c < C4; ++c) acc[c] = (f4)0.f;
    #pragma unroll 4
    for (int r = 0; r < FRL; ++r) {
        int n = n0 + r;
        const float* src = (n < NPREV) ? (prev + (size_t)n * D) : inp;
        float e = s_e[r];
        #pragma unroll
        for (int c = 0; c < C4; ++c) acc[c] += e * ld4(src + 4 * (t + c * THREADS));
    }
    #pragma unroll
    for (int c = 0; c < C4; ++c)
        st4(acc[c], ctxpart + (size_t)blockIdx.x * D + 4 * (t + c * THREADS));
    if (t == 0) { ms[2 * blockIdx.x] = m_b; ms[2 * blockIdx.x + 1] = s_b; }
}

template<int FBL>
__global__ void k_combine_legacy(const float* __restrict__ ms, const float* __restrict__ ctxpart,
                                 float* __restrict__ ctx) {
    __shared__ float sm[2 * FBL];
    int t = threadIdx.x;
    for (int i = t; i < 2 * FBL; i += 256) sm[i] = ms[i];
    __syncthreads();
    float M = -INFINITY;
    #pragma unroll 8
    for (int b = 0; b < FBL; ++b) M = fmaxf(M, sm[2 * b]);
    float S = 0.f;
    #pragma unroll 8
    for (int b = 0; b < FBL; ++b) S += __expf(sm[2 * b] - M) * sm[2 * b + 1];
    int d4 = blockIdx.x * 256 + t;
    f4 a = (f4)0.f;
    #pragma unroll 8
    for (int b = 0; b < FBL; ++b) {
        float w = __expf(sm[2 * b] - M);
        a += w * ld4(ctxpart + (size_t)b * D + 4 * d4);
    }
    a *= (1.f / S);
    st4(a, ctx + 4 * d4);
}

extern "C" void kernel_launch(void* const* d_in, const int* in_sizes, int n_in,
                              void* d_out, int out_size, void* d_ws, size_t ws_size,
                              hipStream_t stream) {
    const float* prev = (const float*)d_in[0];   // (8191, 4096)
    const float* inp  = (const float*)d_in[1];   // (4096,)
    const float* W_Q  = (const float*)d_in[2];
    const float* W_K  = (const float*)d_in[3];
    const float* W_V  = (const float*)d_in[4];
    float* out = (float*)d_out;                  // [0:4096]=output, [4096:]=inputs
    float* io  = out + D;
    float* ws  = (float*)d_ws;

    // main layout: query D | kq D | kqpart 128*D | ms 2*FB | ctxpart FB*D |
    //              ctx2 (FB/64)*D | ctx D
    constexpr int NCH = D / 32;          // 128 kq chunks
    constexpr int BCH = FB / 64;         // 8 ctx chunks
    size_t need_main = (size_t)(2 * D + NCH * D + 2 * FB + (size_t)FB * D + BCH * D + D)
                       * sizeof(float);

    if (ws_size >= need_main) {
        float* query   = ws;
        float* kq      = ws + D;
        float* kqpart  = ws + 2 * D;
        float* ms      = kqpart + (size_t)NCH * D;
        float* ctxpart = ms + 2 * FB;
        float* ctx2    = ctxpart + (size_t)FB * D;
        float* ctx     = ctx2 + (size_t)BCH * D;

        k_matvec_rows<false><<<1024, 256, 0, stream>>>(W_Q, inp, nullptr, query);
        k_colvec_partial<32><<<dim3(4, NCH), 256, 0, stream>>>(W_K, query, kqpart);
        k_reduce_chunks<<<16, 256, 0, stream>>>(kqpart, kq, NCH);
        k_flash<<<FB, 1024, 0, stream>>>(prev, inp, kq, io, ms, ctxpart);
        k_combine1<<<dim3(4, BCH), 256, 0, stream>>>(ms, ctxpart, ctx2);
        k_combine2<<<4, 256, 0, stream>>>(ms, ctx2, ctx, BCH);
        k_matvec_rows<true><<<1024, 256, 0, stream>>>(W_V, ctx, inp, out);
    } else {
        // small-ws fallback: re-read flash, FB=256
        float* query   = ws;
        float* kq      = ws + D;
        float* kqpart  = ws + 2 * D;                       // 64*D
        float* ms      = kqpart + (size_t)64 * D;          // 512
        float* ctxpart = ms + 512;                         // 256*D
        float* ctx     = ctxpart + (size_t)256 * D;        // D

        k_matvec_rows<false><<<1024, 256, 0, stream>>>(W_Q, inp, nullptr, query);
        k_colvec_partial<64><<<dim3(4, 64), 256, 0, stream>>>(W_K, query, kqpart);
        k_reduce_chunks<<<16, 256, 0, stream>>>(kqpart, kq, 64);
        k_flash_legacy<256, 1024><<<256, 1024, 0, stream>>>(prev, inp, kq, io, ms, ctxpart);
        k_combine_legacy<256><<<4, 256, 0, stream>>>(ms, ctxpart, ctx);
        k_matvec_rows<true><<<1024, 256, 0, stream>>>(W_V, ctx, inp, out);
    }
}